// Round 3
// baseline (25937.054 us; speedup 1.0000x reference)
//
#include <hip/hip_runtime.h>
#include <cstdint>
#include <cstddef>

#define BB   64
#define SEQL 512
#define INF  512
#define HID  1024
#define GG   4096   // 4*HID

#define MU_    0.9f
#define SSTEP_ 0.1f
#define BETA_  0.999f
#define EPS_   1e-16f
#define SCL    2048.0f
#define ISCL   (1.0f / 2048.0f)

typedef unsigned short u16;
typedef unsigned int   u32;
typedef _Float16 half8 __attribute__((ext_vector_type(8)));
typedef float f32x4 __attribute__((ext_vector_type(4)));

// D = A*B + C, 16x16x32 f16. Builtin => compiler handles all hazards/waits.
__device__ __forceinline__ f32x4 mfma16(half8 a, half8 b, f32x4 c) {
  return __builtin_amdgcn_mfma_f32_16x16x32_f16(a, b, c, 0, 0, 0);
}

// f32 -> (hi, lo*2048) f16 split: x ~= hi + lo/2048, rel residual ~2^-22.
__device__ __forceinline__ void fsplit(float v, _Float16& hi, _Float16& lo) {
  hi = (_Float16)v;
  lo = (_Float16)((v - (float)hi) * SCL);
}

// ---- transpose + f16-split: src [R][C] f32 -> dhi/dlo [C][R] f16 ----
__global__ __launch_bounds__(256) void transpose_split(const float* __restrict__ src,
                                                       _Float16* __restrict__ dhi,
                                                       _Float16* __restrict__ dlo,
                                                       int R, int C) {
  __shared__ float tile[32][33];
  int c0 = blockIdx.x * 32, r0 = blockIdx.y * 32;
  int tx = threadIdx.x & 31, ty = threadIdx.x >> 5;  // 32 x 8
#pragma unroll
  for (int i = 0; i < 32; i += 8)
    tile[ty + i][tx] = src[(size_t)(r0 + ty + i) * C + (c0 + tx)];
  __syncthreads();
#pragma unroll
  for (int i = 0; i < 32; i += 8) {
    float v = tile[tx][ty + i];
    _Float16 hi, lo;
    fsplit(v, hi, lo);
    size_t o = (size_t)(c0 + ty + i) * R + (r0 + tx);
    dhi[o] = hi;
    dlo[o] = lo;
  }
}

// ---- init: copy c0/v0/m0 into d_out state regions; h0 -> f16 split planes ----
__global__ __launch_bounds__(256) void init_state(const float* __restrict__ h0,
                                                  const float* __restrict__ c0,
                                                  const float* __restrict__ v0,
                                                  const float* __restrict__ m0,
                                                  float* __restrict__ co,
                                                  float* __restrict__ vo,
                                                  float* __restrict__ mo,
                                                  _Float16* __restrict__ hb_hi,
                                                  _Float16* __restrict__ hb_lo) {
  int i = blockIdx.x * 256 + threadIdx.x;
  if (i < BB * GG) { vo[i] = v0[i]; mo[i] = m0[i]; }
  if (i < BB * HID) {
    co[i] = c0[i];
    _Float16 hi, lo;
    fsplit(h0[i], hi, lo);
    hb_hi[i] = hi;
    hb_lo[i] = lo;
  }
}

// ---- grad chunk GEMM (f16-split, ~f32 accuracy):
// grad[tloc][b][g] = sum_k x[b][t][k]*W_ih[k][g] + b_ih[g]
// grid: (Tc, GG/64), block 256 (4 waves). Wave: 16 rows(b) x 64 cols(g).
__global__ __launch_bounds__(256) void grad_gemm(const float* __restrict__ x,
                                                 const _Float16* __restrict__ whi, // [G][IN]
                                                 const _Float16* __restrict__ wlo, // [G][IN]
                                                 const float* __restrict__ bih,
                                                 float* __restrict__ grad,         // [Tc][B][G]
                                                 int t0) {
  int tloc = blockIdx.x;
  int n0 = blockIdx.y * 64;
  int wave = threadIdx.x >> 6, lane = threadIdx.x & 63;
  int l15 = lane & 15, lg = lane >> 4;
  int t = t0 + tloc;
  int b = 16 * wave + l15;
  const float* xa = x + (size_t)b * (SEQL * INF) + (size_t)t * INF + lg * 8;
  const _Float16* wh = whi + (size_t)(n0 + l15) * INF + lg * 8;
  const _Float16* wl = wlo + (size_t)(n0 + l15) * INF + lg * 8;

  f32x4 accM[4] = {};
  f32x4 accL[4] = {};
  for (int kk = 0; kk < INF; kk += 32) {
    f32x4 x0 = *(const f32x4*)(xa + kk);
    f32x4 x1 = *(const f32x4*)(xa + kk + 4);
    half8 ah, al;
#pragma unroll
    for (int j = 0; j < 4; j++) {
      _Float16 hi, lo;
      fsplit(x0[j], hi, lo); ah[j] = hi; al[j] = lo;
      fsplit(x1[j], hi, lo); ah[4 + j] = hi; al[4 + j] = lo;
    }
#pragma unroll
    for (int nt = 0; nt < 4; nt++) {
      half8 bh = *(const half8*)(wh + (size_t)nt * 16 * INF + kk);
      half8 bl = *(const half8*)(wl + (size_t)nt * 16 * INF + kk);
      accM[nt] = mfma16(ah, bh, accM[nt]);
      accL[nt] = mfma16(al, bh, accL[nt]);
      accL[nt] = mfma16(ah, bl, accL[nt]);
    }
  }
#pragma unroll
  for (int nt = 0; nt < 4; nt++) {
    int g = n0 + nt * 16 + l15;
    float bias = bih[g];
#pragma unroll
    for (int r = 0; r < 4; r++) {
      int bo = 16 * wave + lg * 4 + r;
      grad[((size_t)tloc * BB + bo) * GG + g] = accM[nt][r] + accL[nt][r] * ISCL + bias;
    }
  }
}

// ---- one timestep: gates = v'/(sqrt(m')+eps) + h@W_hh + b_hh, LSTM cell update.
// grid: 64 wgs (16 cells each), block 256 (4 waves; wave = 16 batch rows).
__global__ __launch_bounds__(256) void lstm_step(const _Float16* __restrict__ hp_hi, // [B][H]
                                                 const _Float16* __restrict__ hp_lo,
                                                 _Float16* __restrict__ hn_hi,
                                                 _Float16* __restrict__ hn_lo,
                                                 const _Float16* __restrict__ whi,   // [G][H]
                                                 const _Float16* __restrict__ wlo,   // [G][H]
                                                 const float* __restrict__ grad,     // [B][G]
                                                 const float* __restrict__ bhh,
                                                 float* __restrict__ vb,
                                                 float* __restrict__ mb,
                                                 float* __restrict__ cb,
                                                 float* __restrict__ lo,             // [B][S][H]
                                                 float* __restrict__ hfin,           // or null
                                                 int t) {
  int nb = blockIdx.x;
  int wave = threadIdx.x >> 6, lane = threadIdx.x & 63;
  int l15 = lane & 15, lg = lane >> 4;

  const _Float16* hah = hp_hi + (size_t)(16 * wave + l15) * HID + lg * 8;
  const _Float16* hal = hp_lo + (size_t)(16 * wave + l15) * HID + lg * 8;
  const _Float16* wh[4];
  const _Float16* wl[4];
#pragma unroll
  for (int q = 0; q < 4; q++) {
    wh[q] = whi + (size_t)(q * HID + nb * 16 + l15) * HID + lg * 8;
    wl[q] = wlo + (size_t)(q * HID + nb * 16 + l15) * HID + lg * 8;
  }

  f32x4 accM[4] = {};
  f32x4 accL[4] = {};
  for (int kk = 0; kk < HID; kk += 32) {
    half8 ah = *(const half8*)(hah + kk);
    half8 al = *(const half8*)(hal + kk);
#pragma unroll
    for (int q = 0; q < 4; q++) {
      half8 bh = *(const half8*)(wh[q] + kk);
      half8 bl = *(const half8*)(wl[q] + kk);
      accM[q] = mfma16(ah, bh, accM[q]);
      accL[q] = mfma16(al, bh, accL[q]);
      accL[q] = mfma16(ah, bl, accL[q]);
    }
  }

  int n = nb * 16 + l15;
#pragma unroll
  for (int r = 0; r < 4; r++) {
    int bo = 16 * wave + lg * 4 + r;
    float gate[4];
#pragma unroll
    for (int q = 0; q < 4; q++) {
      size_t gi = (size_t)bo * GG + q * HID + n;
      float gr = grad[gi];
      float vv = MU_ * vb[gi] + SSTEP_ * gr;
      float mm = BETA_ * mb[gi] + (1.0f - BETA_) * gr * gr;
      vb[gi] = vv;
      mb[gi] = mm;
      float rec = accM[q][r] + accL[q][r] * ISCL;
      gate[q] = vv / (sqrtf(mm) + EPS_) + rec + bhh[q * HID + n];
    }
    float ig = 1.0f / (1.0f + expf(-gate[0]));
    float fg = 1.0f / (1.0f + expf(-gate[1]));
    float gg = tanhf(gate[2]);
    float og = 1.0f / (1.0f + expf(-gate[3]));
    size_t ci = (size_t)bo * HID + n;
    float cc = cb[ci] * fg + ig * gg;
    cb[ci] = cc;
    float hh = og * tanhf(cc);
    lo[(size_t)bo * (SEQL * HID) + (size_t)t * HID + n] = hh;
    _Float16 hi2, lo2;
    fsplit(hh, hi2, lo2);
    hn_hi[ci] = hi2;
    hn_lo[ci] = lo2;
    if (hfin) hfin[ci] = hh;
  }
}

extern "C" void kernel_launch(void* const* d_in, const int* in_sizes, int n_in,
                              void* d_out, int out_size, void* d_ws, size_t ws_size,
                              hipStream_t stream) {
  const float* x   = (const float*)d_in[0];
  const float* wih = (const float*)d_in[1];
  const float* whh = (const float*)d_in[2];
  const float* bih = (const float*)d_in[3];
  const float* bhh = (const float*)d_in[4];
  const float* h0  = (const float*)d_in[5];
  const float* c0  = (const float*)d_in[6];
  const float* v0  = (const float*)d_in[7];
  const float* m0  = (const float*)d_in[8];

  float* out  = (float*)d_out;
  float* lo   = out;                                  // [B][S][H]
  float* hout = out + (size_t)BB * SEQL * HID;        // [B][H]
  float* cout = hout + (size_t)BB * HID;              // [B][H]
  float* vout = cout + (size_t)BB * HID;              // [B][G]
  float* mout = vout + (size_t)BB * GG;               // [B][G]

  char* ws = (char*)d_ws;
  size_t o = 0;
  _Float16* wih_hi = (_Float16*)(ws + o); o += (size_t)GG * INF * 2;   // 4 MiB
  _Float16* wih_lo = (_Float16*)(ws + o); o += (size_t)GG * INF * 2;   // 4 MiB
  _Float16* whh_hi = (_Float16*)(ws + o); o += (size_t)GG * HID * 2;   // 8 MiB
  _Float16* whh_lo = (_Float16*)(ws + o); o += (size_t)GG * HID * 2;   // 8 MiB
  _Float16* hb = (_Float16*)(ws + o);     o += (size_t)4 * BB * HID * 2; // 512 KiB
  float* gradws = (float*)(ws + o);

  const size_t STEP_BYTES = (size_t)BB * GG * sizeof(float);  // 1 MiB
  size_t cap = (ws_size > o) ? (ws_size - o) / STEP_BYTES : 1;
  if (cap < 1) cap = 1;
  int Tc = (int)(cap < (size_t)SEQL ? cap : (size_t)SEQL);

  // h split planes: [buf][plane][B][H]
  _Float16* h_hi0 = hb;
  _Float16* h_lo0 = hb + (size_t)BB * HID;
  _Float16* h_hi1 = hb + (size_t)2 * BB * HID;
  _Float16* h_lo1 = hb + (size_t)3 * BB * HID;

  transpose_split<<<dim3(GG / 32, INF / 32), 256, 0, stream>>>(wih, wih_hi, wih_lo, INF, GG);
  transpose_split<<<dim3(GG / 32, HID / 32), 256, 0, stream>>>(whh, whh_hi, whh_lo, HID, GG);
  init_state<<<(BB * GG) / 256, 256, 0, stream>>>(h0, c0, v0, m0, cout, vout, mout, h_hi0, h_lo0);

  for (int t0 = 0; t0 < SEQL; t0 += Tc) {
    int T = (SEQL - t0 < Tc) ? (SEQL - t0) : Tc;
    grad_gemm<<<dim3(T, GG / 64), 256, 0, stream>>>(x, wih_hi, wih_lo, bih, gradws, t0);
    for (int tt = 0; tt < T; tt++) {
      int t = t0 + tt;
      int pb = t & 1;
      lstm_step<<<64, 256, 0, stream>>>(
          pb ? h_hi1 : h_hi0, pb ? h_lo1 : h_lo0,
          pb ? h_hi0 : h_hi1, pb ? h_lo0 : h_lo1,
          whh_hi, whh_lo,
          gradws + (size_t)tt * BB * GG, bhh,
          vout, mout, cout, lo,
          (t == SEQL - 1) ? hout : (float*)nullptr, t);
    }
  }
}